// Round 9
// baseline (1003.717 us; speedup 1.0000x reference)
//
#include <hip/hip_runtime.h>
#include <hip/hip_bf16.h>

#define TEMP_INV (1.0f / 0.07f)
#define LOG2E 1.4426950408889634f
#define LN2 0.6931471805599453f
#define CFIX 21.0f

typedef __attribute__((ext_vector_type(4))) float f32x4;
typedef __attribute__((ext_vector_type(8))) short bf16x8;

__device__ __forceinline__ ushort f2bf(float x) {
  union { float f; unsigned u; } v; v.f = x;
  unsigned r = (v.u + 0x7fffu + ((v.u >> 16) & 1u)) >> 16;
  return (ushort)r;
}

__device__ __forceinline__ void gload16(const ushort* g, ushort* l) {
  __builtin_amdgcn_global_load_lds(
      (const __attribute__((address_space(1))) void*)g,
      (__attribute__((address_space(3))) void*)l, 16, 0, 0);
}

// ---------------- Kernel 0: zero the row-sum accumulator ---------------------
__global__ __launch_bounds__(256) void zero_kernel(float* __restrict__ p, int n) {
  const int i = blockIdx.x * 256 + threadIdx.x;
  if (i < n) p[i] = 0.f;
}

// ---------------- Kernel 1: L2-normalize rows, write bf16 feats, cross dot ----
__global__ __launch_bounds__(256) void norm_kernel(
    const float* __restrict__ A, const float* __restrict__ P,
    ushort* __restrict__ F, float* __restrict__ cross, int B, int D) {
  const int row = blockIdx.x;
  const int t = threadIdx.x;
  const float4* a4 = reinterpret_cast<const float4*>(A + (size_t)row * D);
  const float4* p4 = reinterpret_cast<const float4*>(P + (size_t)row * D);
  const int n4 = D >> 2;
  float sa = 0.f, sp = 0.f, sx = 0.f;
  for (int i = t; i < n4; i += 256) {
    float4 av = a4[i], pv = p4[i];
    sa += av.x * av.x + av.y * av.y + av.z * av.z + av.w * av.w;
    sp += pv.x * pv.x + pv.y * pv.y + pv.z * pv.z + pv.w * pv.w;
    sx += av.x * pv.x + av.y * pv.y + av.z * pv.z + av.w * pv.w;
  }
#pragma unroll
  for (int off = 32; off; off >>= 1) {
    sa += __shfl_down(sa, off);
    sp += __shfl_down(sp, off);
    sx += __shfl_down(sx, off);
  }
  __shared__ float red[3][4];
  const int wid = t >> 6, lane = t & 63;
  if (lane == 0) { red[0][wid] = sa; red[1][wid] = sp; red[2][wid] = sx; }
  __syncthreads();
  sa = red[0][0] + red[0][1] + red[0][2] + red[0][3];
  sp = red[1][0] + red[1][1] + red[1][2] + red[1][3];
  sx = red[2][0] + red[2][1] + red[2][2] + red[2][3];
  const float ia = rsqrtf(sa), ip = rsqrtf(sp);
  ushort* fa = F + (size_t)row * D;
  ushort* fp = F + (size_t)(B + row) * D;
  for (int i = t; i < n4; i += 256) {
    float4 av = a4[i], pv = p4[i];
    ushort4 oa, op;
    oa.x = f2bf(av.x * ia); oa.y = f2bf(av.y * ia);
    oa.z = f2bf(av.z * ia); oa.w = f2bf(av.w * ia);
    op.x = f2bf(pv.x * ip); op.y = f2bf(pv.y * ip);
    op.z = f2bf(pv.z * ip); op.w = f2bf(pv.w * ip);
    reinterpret_cast<ushort4*>(fa)[i] = oa;
    reinterpret_cast<ushort4*>(fp)[i] = op;
  }
  if (t == 0) cross[row] = sx * ia * ip;
}

// ---------------- Kernel 2: triangular fused Gram + dual-side exp sums -------
// 256x256 triangle tiles (bx<=by), FULL K=1024, 8 waves (2x4), 16x16x32 MFMA,
// BK=32 double-buffer -> 64KB LDS -> 2 blocks/CU co-resident.
// SAFE drain-loop (R8 NaN lesson: every LDS read must be covered by a vmcnt
// placed BEFORE the read with a barrier in between):
//   per K-step v: {vmcnt(0); barrier; read frags(buf v); stage(v+1 -> buf^1);
//                  MFMA x32}
// Coverage: reads follow vmcnt(0)+barrier => all waves' stage(v) landed.
// Overwrite of buf(v) is issued at iter v+1 after its barrier, by which time
// iter-v reads were consumed (compiler lgkmcnt before MFMA use).
// LDS region (256x32 bf16, 16KB) layout verified 0-conflict R2/R3/R6/R7:
//   (trow,k): lrow=trow>>1; slot=(trow&1)*4+(k>>3); c=slot^(lrow&7);
//   byte=lrow*128+c*16+(k&7)*2.
#define VT 32  /* K-32 steps: D/32 */

__global__ __launch_bounds__(512, 4) void gram_lse_kernel(
    const ushort* __restrict__ F, float* __restrict__ lsum, int NN, int D) {
  __shared__ ushort lds[2][2][8192];  // [buf][A=0/B=1][16KB region] = 64KB
  const int nrb = NN >> 8;
  const int ntri = nrb * (nrb + 1) / 2;
  int lin = blockIdx.x;
  if ((ntri & 7) == 0) {  // bijective XCD swizzle (528 = 8*66)
    const int per = ntri >> 3;
    lin = (lin & 7) * per + (lin >> 3);
  }
  int by = (int)((sqrtf(8.f * (float)lin + 1.f) - 1.f) * 0.5f);
  while ((by + 1) * (by + 2) / 2 <= lin) ++by;
  while (by * (by + 1) / 2 > lin) --by;
  const int bx = lin - by * (by + 1) / 2;  // bx <= by
  const int r0 = bx * 256;  // i rows (B operand, N side)
  const int c0 = by * 256;  // j rows (A operand, M side)
  const bool diag = (bx == by);

  const int t = threadIdx.x;
  const int lane = t & 63, w = t >> 6;
  const int lo = lane & 15, hi = lane >> 4;
  const int wr = w >> 2, wn = w & 3;  // wr: j-half(128), wn: i-quarter(64)

  // staging map (per thread): segments w and w+8 of each 16KB region
  const int l3 = lane >> 3, l7 = lane & 7;
  const int cu = l7 ^ l3;
  const int sub = cu >> 2, kc = cu & 3;
  const int trow0 = w * 16 + l3 * 2 + sub;
  const int trow1 = (w + 8) * 16 + l3 * 2 + sub;
  const ushort* srcA0 = F + (size_t)(c0 + trow0) * D + kc * 8;
  const ushort* srcA1 = F + (size_t)(c0 + trow1) * D + kc * 8;
  const ushort* srcB0 = F + (size_t)(r0 + trow0) * D + kc * 8;
  const ushort* srcB1 = F + (size_t)(r0 + trow1) * D + kc * 8;
  const int dst0 = w * 512, dst1 = (w + 8) * 512;  // ushort offsets (uniform)

  // fragment read base (bytes within a region) — verified 0-conflict
  const int cA = (((lo & 1) << 2) | hi) ^ (lo >> 1);
  const int rdBase = (lo >> 1) * 128 + cA * 16;

#define STAGE(V, BUF)                                              \
  do {                                                             \
    int v_ = (V); if (v_ > VT - 1) v_ = VT - 1;                    \
    const size_t o_ = (size_t)v_ * 32;                             \
    gload16(srcA0 + o_, &lds[BUF][0][dst0]);                       \
    gload16(srcA1 + o_, &lds[BUF][0][dst1]);                       \
    gload16(srcB0 + o_, &lds[BUF][1][dst0]);                       \
    gload16(srcB1 + o_, &lds[BUF][1][dst1]);                       \
  } while (0)

  f32x4 acc[8][4];
#pragma unroll
  for (int a = 0; a < 8; ++a)
#pragma unroll
    for (int b = 0; b < 4; ++b) acc[a][b] = (f32x4){0.f, 0.f, 0.f, 0.f};

  STAGE(0, 0);  // prologue

  for (int v = 0; v < VT; ++v) {
    const int buf = v & 1;
    // all of stage(v) (4 instrs/wave) must land before any read of buf(v)
    asm volatile("s_waitcnt vmcnt(0)" ::: "memory");
    __builtin_amdgcn_s_barrier();
    asm volatile("" ::: "memory");

    const char* RA = (const char*)&lds[buf][0][0];
    const char* RB = (const char*)&lds[buf][1][0];
    bf16x8 bfr[4], af[8];
#pragma unroll
    for (int nf = 0; nf < 4; ++nf)
      bfr[nf] = *(const bf16x8*)(RB + wn * 4096 + nf * 1024 + rdBase);
#pragma unroll
    for (int m = 0; m < 8; ++m)
      af[m] = *(const bf16x8*)(RA + wr * 8192 + m * 1024 + rdBase);

    STAGE(v + 1, buf ^ 1);  // next tile into other buffer (clamped at tail)

    __builtin_amdgcn_s_setprio(1);
#pragma unroll
    for (int m = 0; m < 8; ++m)
#pragma unroll
      for (int nf = 0; nf < 4; ++nf)
        acc[m][nf] = __builtin_amdgcn_mfma_f32_16x16x32_bf16(
            af[m], bfr[nf], acc[m][nf], 0, 0, 0);
    __builtin_amdgcn_s_setprio(0);
    asm volatile("" ::: "memory");
  }

  // ---- dual-side epilogue (verbatim from R6/R7, absmax-0 verified) ----
  // acc[mf][nf][rg]: j = c0 + wr*128 + mf*16 + hi*4 + rg
  //                  i = r0 + wn*64 + nf*16 + lo
  const float scl = LOG2E * TEMP_INV;
  float s_i[4] = {0.f, 0.f, 0.f, 0.f};
  float s_j[32];
#pragma unroll
  for (int q = 0; q < 32; ++q) s_j[q] = 0.f;
  {
    const int jb2 = c0 + wr * 128;
#pragma unroll
    for (int nf = 0; nf < 4; ++nf) {
      const int dg = (r0 + wn * 64 + nf * 16 + lo) - jb2;
#pragma unroll
      for (int mf = 0; mf < 8; ++mf)
#pragma unroll
        for (int rg = 0; rg < 4; ++rg) {
          const int jloc = mf * 16 + hi * 4 + rg;
          float e = exp2f(acc[mf][nf][rg] * scl - CFIX);
          if (diag && dg == jloc) e = 0.f;
          s_i[nf] += e;
          s_j[mf * 4 + rg] += e;
        }
    }
  }
  // i-side: reduce over hi groups (this wave's j coverage), add to rows i
#pragma unroll
  for (int nf = 0; nf < 4; ++nf) {
    float v = s_i[nf];
    v += __shfl_xor(v, 16);
    v += __shfl_xor(v, 32);
    if (hi == 0) atomicAdd(&lsum[r0 + wn * 64 + nf * 16 + lo], v);
  }
  // j-side: reduce over lo lanes (this wave's i coverage), add to rows j
  if (!diag) {
#pragma unroll
    for (int q = 0; q < 32; ++q) {
      float v = s_j[q];
      v += __shfl_xor(v, 1);
      v += __shfl_xor(v, 2);
      v += __shfl_xor(v, 4);
      v += __shfl_xor(v, 8);
      if (lo == 0)
        atomicAdd(&lsum[c0 + wr * 128 + (q >> 2) * 16 + hi * 4 + (q & 3)], v);
    }
  }

  asm volatile("s_waitcnt vmcnt(0)" ::: "memory");
#undef STAGE
}

// ---------------- Kernel 3a: per-row loss -> per-block partial sums ----------
__global__ __launch_bounds__(256) void finalize_part(
    const float* __restrict__ lsum, const float* __restrict__ cross,
    const int* __restrict__ labels, float* __restrict__ bsum,
    float* __restrict__ bcnt, int B) {
  const int NN = 2 * B;
  const int i = blockIdx.x * 256 + threadIdx.x;
  float sum = 0.f, cnt = 0.f;
  if (i < NN) {
    const float lse = LN2 * (CFIX + log2f(lsum[i]));
    const float lab = (float)labels[i % B];
    sum = (lse - cross[i % B] * TEMP_INV) * lab;
    cnt = lab;
  }
#pragma unroll
  for (int off = 32; off; off >>= 1) {
    sum += __shfl_down(sum, off);
    cnt += __shfl_down(cnt, off);
  }
  __shared__ float rs[4], rc[4];
  const int wid = threadIdx.x >> 6, lane = threadIdx.x & 63;
  if (lane == 0) { rs[wid] = sum; rc[wid] = cnt; }
  __syncthreads();
  if (threadIdx.x == 0) {
    bsum[blockIdx.x] = rs[0] + rs[1] + rs[2] + rs[3];
    bcnt[blockIdx.x] = rc[0] + rc[1] + rc[2] + rc[3];
  }
}

// ---------------- Kernel 3b: final reduce ------------------------------------
__global__ __launch_bounds__(64) void finalize_final(
    const float* __restrict__ bsum, const float* __restrict__ bcnt,
    float* __restrict__ out, int nb) {
  const int t = threadIdx.x;
  float s = (t < nb) ? bsum[t] : 0.f;
  float c = (t < nb) ? bcnt[t] : 0.f;
#pragma unroll
  for (int off = 32; off; off >>= 1) {
    s += __shfl_down(s, off);
    c += __shfl_down(c, off);
  }
  if (t == 0) out[0] = (c > 0.f) ? s / c : 0.f;
}

extern "C" void kernel_launch(void* const* d_in, const int* in_sizes, int n_in,
                              void* d_out, int out_size, void* d_ws, size_t ws_size,
                              hipStream_t stream) {
  const float* A = (const float*)d_in[0];
  const float* P = (const float*)d_in[1];
  const int* labels = (const int*)d_in[2];
  float* out = (float*)d_out;
  const int B = in_sizes[2];
  const int D = in_sizes[0] / B;
  const int NN = 2 * B;

  char* ws = (char*)d_ws;
  ushort* F = (ushort*)ws;
  size_t off = (size_t)NN * D * sizeof(ushort);
  off = (off + 255) & ~(size_t)255;
  float* cross = (float*)(ws + off);
  off += (size_t)B * sizeof(float);
  off = (off + 255) & ~(size_t)255;
  float* lsum = (float*)(ws + off);
  off += (size_t)NN * sizeof(float);
  off = (off + 255) & ~(size_t)255;
  float* bsum = (float*)(ws + off);
  off += 64 * sizeof(float);
  float* bcnt = (float*)(ws + off);

  zero_kernel<<<(NN + 255) / 256, 256, 0, stream>>>(lsum, NN);
  norm_kernel<<<B, 256, 0, stream>>>(A, P, F, cross, B, D);
  const int nrb = NN >> 8;               // 32 row-panels of 256
  const int ntri = nrb * (nrb + 1) / 2;  // 528 triangle tiles, full K each
  gram_lse_kernel<<<ntri, 512, 0, stream>>>(F, lsum, NN, D);
  const int nb = (NN + 255) / 256;  // 32
  finalize_part<<<nb, 256, 0, stream>>>(lsum, cross, labels, bsum, bcnt, B);
  finalize_final<<<1, 64, 0, stream>>>(bsum, bcnt, out, nb);
}

// Round 10
// 128.845 us; speedup vs baseline: 7.7901x; 7.7901x over previous
//
#include <hip/hip_runtime.h>
#include <hip/hip_bf16.h>

#define TEMP_INV (1.0f / 0.07f)
#define LOG2E 1.4426950408889634f
#define LN2 0.6931471805599453f
#define CFIX 21.0f

typedef __attribute__((ext_vector_type(4))) float f32x4;
typedef __attribute__((ext_vector_type(8))) short bf16x8;

__device__ __forceinline__ ushort f2bf(float x) {
  union { float f; unsigned u; } v; v.f = x;
  unsigned r = (v.u + 0x7fffu + ((v.u >> 16) & 1u)) >> 16;
  return (ushort)r;
}

__device__ __forceinline__ void gload16(const ushort* g, ushort* l) {
  __builtin_amdgcn_global_load_lds(
      (const __attribute__((address_space(1))) void*)g,
      (__attribute__((address_space(3))) void*)l, 16, 0, 0);
}

// ---------------- Kernel 1: L2-normalize rows -> bf16 feats, cross dot, ------
// ---------------- and zero the lsum accumulator (folded zero_kernel) ---------
__global__ __launch_bounds__(256) void norm_kernel(
    const float* __restrict__ A, const float* __restrict__ P,
    ushort* __restrict__ F, float* __restrict__ cross,
    float* __restrict__ lsum, int B, int D) {
  const int row = blockIdx.x;
  const int t = threadIdx.x;
  // fold in lsum zeroing: rows 0..(2B/256-1) clear 256 floats each
  {
    const int zi = row * 256 + t;
    if (zi < 2 * B) lsum[zi] = 0.f;
  }
  const float4* a4 = reinterpret_cast<const float4*>(A + (size_t)row * D);
  const float4* p4 = reinterpret_cast<const float4*>(P + (size_t)row * D);
  const int n4 = D >> 2;
  float sa = 0.f, sp = 0.f, sx = 0.f;
  for (int i = t; i < n4; i += 256) {
    float4 av = a4[i], pv = p4[i];
    sa += av.x * av.x + av.y * av.y + av.z * av.z + av.w * av.w;
    sp += pv.x * pv.x + pv.y * pv.y + pv.z * pv.z + pv.w * pv.w;
    sx += av.x * pv.x + av.y * pv.y + av.z * pv.z + av.w * pv.w;
  }
#pragma unroll
  for (int off = 32; off; off >>= 1) {
    sa += __shfl_down(sa, off);
    sp += __shfl_down(sp, off);
    sx += __shfl_down(sx, off);
  }
  __shared__ float red[3][4];
  const int wid = t >> 6, lane = t & 63;
  if (lane == 0) { red[0][wid] = sa; red[1][wid] = sp; red[2][wid] = sx; }
  __syncthreads();
  sa = red[0][0] + red[0][1] + red[0][2] + red[0][3];
  sp = red[1][0] + red[1][1] + red[1][2] + red[1][3];
  sx = red[2][0] + red[2][1] + red[2][2] + red[2][3];
  const float ia = rsqrtf(sa), ip = rsqrtf(sp);
  ushort* fa = F + (size_t)row * D;
  ushort* fp = F + (size_t)(B + row) * D;
  for (int i = t; i < n4; i += 256) {
    float4 av = a4[i], pv = p4[i];
    ushort4 oa, op;
    oa.x = f2bf(av.x * ia); oa.y = f2bf(av.y * ia);
    oa.z = f2bf(av.z * ia); oa.w = f2bf(av.w * ia);
    op.x = f2bf(pv.x * ip); op.y = f2bf(pv.y * ip);
    op.z = f2bf(pv.z * ip); op.w = f2bf(pv.w * ip);
    reinterpret_cast<ushort4*>(fa)[i] = oa;
    reinterpret_cast<ushort4*>(fp)[i] = op;
  }
  if (t == 0) cross[row] = sx * ia * ip;
}

// ---------------- Kernel 2: packed triangular fused Gram ---------------------
// Grid = min(ntri,256) persistent blocks; block b runs its CONTIGUOUS range of
// 2-3 triangle tiles (consecutive tiles share by -> A-panel L2-warm).
// Per tile: R6's verified 8-phase BK=64 dbuf schedule (byte-identical PHASE/
// STAGE/prologue/vmcnt discipline) + R6's dual-side epilogue. Between tiles:
// vmcnt(0)+barrier (stale clamped prefetches vs next prologue WAR).
// 1 block/CU (128KB LDS); __launch_bounds__(512,2) — R9 lesson: acc[8][4]
// needs ~200 unified regs, so min-waves/EU must stay 2 (cap 256), never 4.
// LDS region (256x32 bf16, 16KB) layout verified 0-conflict R2/R3/R6:
//   (trow,k): lrow=trow>>1; slot=(trow&1)*4+(k>>3); c=slot^(lrow&7);
//   byte=lrow*128+c*16+(k&7)*2.
#define VT 16  /* K-64 tiles per full-K tile: D/64 */

__global__ __launch_bounds__(512, 2) void gram_lse_kernel(
    const ushort* __restrict__ F, float* __restrict__ lsum, int NN, int D) {
  __shared__ ushort lds[2][2][2][8192];  // [buf][A=0/B=1][khalf][16KB region]
  const int nrb = NN >> 8;
  const int ntri = nrb * (nrb + 1) / 2;
  const int nblk = gridDim.x;
  const int base = ntri / nblk, rem = ntri - base * nblk;
  const int bid = blockIdx.x;
  const int nMine = base + (bid < rem ? 1 : 0);
  const int sMine = bid * base + (bid < rem ? bid : rem);

  const int t = threadIdx.x;
  const int lane = t & 63, w = t >> 6;
  const int lo = lane & 15, hi = lane >> 4;
  const int wr = w >> 2, wn = w & 3;  // wr: j-half(128), wn: i-quarter(64)

  // staging map (per thread): segments w and w+8 of each 16KB region
  const int l3 = lane >> 3, l7 = lane & 7;
  const int cu = l7 ^ l3;
  const int sub = cu >> 2, kc = cu & 3;
  const int trow0 = w * 16 + l3 * 2 + sub;
  const int trow1 = (w + 8) * 16 + l3 * 2 + sub;
  const int dst0 = w * 512, dst1 = (w + 8) * 512;  // ushort offsets (uniform)

  // fragment read base (bytes within a region) — verified 0-conflict
  const int cA = (((lo & 1) << 2) | hi) ^ (lo >> 1);
  const int rdBase = (lo >> 1) * 128 + cA * 16;

  const float scl = LOG2E * TEMP_INV;

  for (int ti = 0; ti < nMine; ++ti) {
    const int lin = sMine + ti;
    int by = (int)((sqrtf(8.f * (float)lin + 1.f) - 1.f) * 0.5f);
    while ((by + 1) * (by + 2) / 2 <= lin) ++by;
    while (by * (by + 1) / 2 > lin) --by;
    const int bx = lin - by * (by + 1) / 2;  // bx <= by
    const int r0 = bx * 256;  // i rows (B operand, N side)
    const int c0 = by * 256;  // j rows (A operand, M side)
    const bool diag = (bx == by);

    const ushort* srcA0 = F + (size_t)(c0 + trow0) * D + kc * 8;
    const ushort* srcA1 = F + (size_t)(c0 + trow1) * D + kc * 8;
    const ushort* srcB0 = F + (size_t)(r0 + trow0) * D + kc * 8;
    const ushort* srcB1 = F + (size_t)(r0 + trow1) * D + kc * 8;

#define STAGE_A(T, KS, BUF)                                              \
  do {                                                                   \
    int c_ = (T); if (c_ > VT - 1) c_ = VT - 1;                          \
    const size_t o_ = (size_t)(c_ * 64 + (KS) * 32);                     \
    gload16(srcA0 + o_, &lds[BUF][0][KS][dst0]);                         \
    gload16(srcA1 + o_, &lds[BUF][0][KS][dst1]);                         \
  } while (0)
#define STAGE_B(T, KS, BUF)                                              \
  do {                                                                   \
    int c_ = (T); if (c_ > VT - 1) c_ = VT - 1;                          \
    const size_t o_ = (size_t)(c_ * 64 + (KS) * 32);                     \
    gload16(srcB0 + o_, &lds[BUF][1][KS][dst0]);                         \
    gload16(srcB1 + o_, &lds[BUF][1][KS][dst1]);                         \
  } while (0)

    f32x4 acc[8][4];
    bf16x8 bfr[4];

#define PHASE(BUF, MH, KS, READB, STAGE_STMT, WAIT4)                          \
  do {                                                                        \
    const char* RA_ = (const char*)&lds[BUF][0][KS][0];                       \
    const char* RB_ = (const char*)&lds[BUF][1][KS][0];                       \
    if (READB) {                                                              \
      _Pragma("unroll") for (int nf = 0; nf < 4; ++nf)                        \
          bfr[nf] = *(const bf16x8*)(RB_ + wn * 4096 + nf * 1024 + rdBase);   \
    }                                                                         \
    bf16x8 af[4];                                                             \
    _Pragma("unroll") for (int m = 0; m < 4; ++m)                             \
        af[m] = *(const bf16x8*)(RA_ + wr * 8192 + ((MH)*4 + m) * 1024 +      \
                                 rdBase);                                     \
    STAGE_STMT;                                                               \
    if (WAIT4) asm volatile("s_waitcnt vmcnt(4)" ::: "memory");               \
    asm volatile("" ::: "memory");                                            \
    __builtin_amdgcn_s_barrier();                                             \
    asm volatile("" ::: "memory");                                            \
    __builtin_amdgcn_s_setprio(1);                                            \
    _Pragma("unroll") for (int m = 0; m < 4; ++m)                             \
      _Pragma("unroll") for (int nf = 0; nf < 4; ++nf)                        \
          acc[(MH)*4 + m][nf] = __builtin_amdgcn_mfma_f32_16x16x32_bf16(      \
              af[m], bfr[nf], acc[(MH)*4 + m][nf], 0, 0, 0);                  \
    __builtin_amdgcn_s_setprio(0);                                            \
    asm volatile("" ::: "memory");                                            \
    __builtin_amdgcn_s_barrier();                                             \
    asm volatile("" ::: "memory");                                            \
  } while (0)

#pragma unroll
    for (int a = 0; a < 8; ++a)
#pragma unroll
      for (int b = 0; b < 4; ++b) acc[a][b] = (f32x4){0.f, 0.f, 0.f, 0.f};

    // prologue: 7 half-tiles (A1k1 is staged by iter0's P1)
    STAGE_A(0, 0, 0); STAGE_B(0, 0, 0);
    STAGE_A(0, 1, 0); STAGE_B(0, 1, 0);
    STAGE_A(1, 0, 1); STAGE_B(1, 0, 1);
    STAGE_B(1, 1, 1);
    asm volatile("s_waitcnt vmcnt(6)" ::: "memory");
    __builtin_amdgcn_s_barrier();
    asm volatile("" ::: "memory");

    for (int it = 0; it < 8; ++it) {
      const int tt = it * 2;  // even tile -> buf0; odd -> buf1
      PHASE(0, 0, 0, true,  STAGE_A(tt + 1, 1, 1), false);  // P1
      PHASE(0, 1, 0, false, STAGE_B(tt + 2, 0, 0), false);  // P2
      PHASE(0, 0, 1, true,  STAGE_A(tt + 2, 0, 0), false);  // P3
      PHASE(0, 1, 1, false, STAGE_B(tt + 2, 1, 0), true);   // P4 vmcnt(4)
      PHASE(1, 0, 0, true,  STAGE_A(tt + 2, 1, 0), false);  // P5
      PHASE(1, 1, 0, false, STAGE_B(tt + 3, 0, 1), false);  // P6
      PHASE(1, 0, 1, true,  STAGE_A(tt + 3, 0, 1), false);  // P7
      PHASE(1, 1, 1, false, STAGE_B(tt + 3, 1, 1), true);   // P8 vmcnt(4)
    }

    // ---- dual-side epilogue (verbatim R6, absmax-0 verified) ----
    // acc[mf][nf][rg]: j = c0 + wr*128 + mf*16 + hi*4 + rg
    //                  i = r0 + wn*64 + nf*16 + lo
    float s_i[4] = {0.f, 0.f, 0.f, 0.f};
    float s_j[32];
#pragma unroll
    for (int q = 0; q < 32; ++q) s_j[q] = 0.f;
    {
      const int jb2 = c0 + wr * 128;
#pragma unroll
      for (int nf = 0; nf < 4; ++nf) {
        const int dg = (r0 + wn * 64 + nf * 16 + lo) - jb2;
#pragma unroll
        for (int mf = 0; mf < 8; ++mf)
#pragma unroll
          for (int rg = 0; rg < 4; ++rg) {
            const int jloc = mf * 16 + hi * 4 + rg;
            float e = exp2f(acc[mf][nf][rg] * scl - CFIX);
            if (diag && dg == jloc) e = 0.f;
            s_i[nf] += e;
            s_j[mf * 4 + rg] += e;
          }
      }
    }
    // i-side: reduce over hi groups (this wave's j coverage), add to rows i
#pragma unroll
    for (int nf = 0; nf < 4; ++nf) {
      float v = s_i[nf];
      v += __shfl_xor(v, 16);
      v += __shfl_xor(v, 32);
      if (hi == 0) atomicAdd(&lsum[r0 + wn * 64 + nf * 16 + lo], v);
    }
    // j-side: reduce over lo lanes (this wave's i coverage), add to rows j
    if (!diag) {
#pragma unroll
      for (int q = 0; q < 32; ++q) {
        float v = s_j[q];
        v += __shfl_xor(v, 1);
        v += __shfl_xor(v, 2);
        v += __shfl_xor(v, 4);
        v += __shfl_xor(v, 8);
        if (lo == 0)
          atomicAdd(&lsum[c0 + wr * 128 + (q >> 2) * 16 + hi * 4 + (q & 3)], v);
      }
    }

    // drain stale clamped prefetches before next tile's prologue overwrites
    asm volatile("s_waitcnt vmcnt(0)" ::: "memory");
    __builtin_amdgcn_s_barrier();
    asm volatile("" ::: "memory");
#undef PHASE
#undef STAGE_A
#undef STAGE_B
  }
}

// ---------------- Kernel 3a: per-row loss -> per-block partial sums ----------
__global__ __launch_bounds__(256) void finalize_part(
    const float* __restrict__ lsum, const float* __restrict__ cross,
    const int* __restrict__ labels, float* __restrict__ bsum,
    float* __restrict__ bcnt, int B) {
  const int NN = 2 * B;
  const int i = blockIdx.x * 256 + threadIdx.x;
  float sum = 0.f, cnt = 0.f;
  if (i < NN) {
    const float lse = LN2 * (CFIX + log2f(lsum[i]));
    const float lab = (float)labels[i % B];
    sum = (lse - cross[i % B] * TEMP_INV) * lab;
    cnt = lab;
  }
#pragma unroll
  for (int off = 32; off; off >>= 1) {
    sum += __shfl_down(sum, off);
    cnt += __shfl_down(cnt, off);
  }
  __shared__ float rs[4], rc[4];
  const int wid = threadIdx.x >> 6, lane = threadIdx.x & 63;
  if (lane == 0) { rs[wid] = sum; rc[wid] = cnt; }
  __syncthreads();
  if (threadIdx.x == 0) {
    bsum[blockIdx.x] = rs[0] + rs[1] + rs[2] + rs[3];
    bcnt[blockIdx.x] = rc[0] + rc[1] + rc[2] + rc[3];
  }
}

// ---------------- Kernel 3b: final reduce ------------------------------------
__global__ __launch_bounds__(64) void finalize_final(
    const float* __restrict__ bsum, const float* __restrict__ bcnt,
    float* __restrict__ out, int nb) {
  const int t = threadIdx.x;
  float s = (t < nb) ? bsum[t] : 0.f;
  float c = (t < nb) ? bcnt[t] : 0.f;
#pragma unroll
  for (int off = 32; off; off >>= 1) {
    s += __shfl_down(s, off);
    c += __shfl_down(c, off);
  }
  if (t == 0) out[0] = (c > 0.f) ? s / c : 0.f;
}

extern "C" void kernel_launch(void* const* d_in, const int* in_sizes, int n_in,
                              void* d_out, int out_size, void* d_ws, size_t ws_size,
                              hipStream_t stream) {
  const float* A = (const float*)d_in[0];
  const float* P = (const float*)d_in[1];
  const int* labels = (const int*)d_in[2];
  float* out = (float*)d_out;
  const int B = in_sizes[2];
  const int D = in_sizes[0] / B;
  const int NN = 2 * B;

  char* ws = (char*)d_ws;
  ushort* F = (ushort*)ws;
  size_t off = (size_t)NN * D * sizeof(ushort);
  off = (off + 255) & ~(size_t)255;
  float* cross = (float*)(ws + off);
  off += (size_t)B * sizeof(float);
  off = (off + 255) & ~(size_t)255;
  float* lsum = (float*)(ws + off);
  off += (size_t)NN * sizeof(float);
  off = (off + 255) & ~(size_t)255;
  float* bsum = (float*)(ws + off);
  off += 64 * sizeof(float);
  float* bcnt = (float*)(ws + off);

  norm_kernel<<<B, 256, 0, stream>>>(A, P, F, cross, lsum, B, D);
  const int nrb = NN >> 8;               // 32 row-panels of 256
  const int ntri = nrb * (nrb + 1) / 2;  // 528 triangle tiles, full K each
  const int nblk = (ntri < 256) ? ntri : 256;  // packed persistent blocks
  gram_lse_kernel<<<nblk, 512, 0, stream>>>(F, lsum, NN, D);
  const int nb = (NN + 255) / 256;  // 32
  finalize_part<<<nb, 256, 0, stream>>>(lsum, cross, labels, bsum, bcnt, B);
  finalize_final<<<1, 64, 0, stream>>>(bsum, bcnt, out, nb);
}